// Round 8
// baseline (165.056 us; speedup 1.0000x reference)
//
#include <hip/hip_runtime.h>
#include <math.h>

#define NB 128
#define NT 2048
#define ND 256
#define NE 32
#define NL 8
#define NP 168
#define SCL 0.0625f   // 1/sqrt(256)

// workspace float offsets
#define OFF_QK   0          // 8*256
#define OFF_WVO  4096       // 65536   w_ctx_v @ w_lat_out
#define OFF_WVW  69632      // 65536   wlv @ (wso @ gw1b)
#define OFF_G0   135168     // 168*256
#define OFF_Q2S  178176     // 168*256
#define OFF_AV   221184     // 4096 pi * 8 l * 256 d = 8388608
#define OFF_DEN  8609792    // 4096 pi * 8
#define OFF_K2   8642560    // 128*8*256
#define OFF_VW   8904704    // 128*8*256

typedef __attribute__((ext_vector_type(8))) short short8b;
typedef __attribute__((ext_vector_type(4))) float f32x4;

static __device__ __forceinline__ unsigned short f2bf(float f){
  unsigned u = __float_as_uint(f);
  u += 0x7fffu + ((u >> 16) & 1u);
  return (unsigned short)(u >> 16);
}

static __device__ __forceinline__ short8b pack8(float4 lo, float4 hi){
  short8b r;
  r[0]=(short)f2bf(lo.x); r[1]=(short)f2bf(lo.y); r[2]=(short)f2bf(lo.z); r[3]=(short)f2bf(lo.w);
  r[4]=(short)f2bf(hi.x); r[5]=(short)f2bf(hi.y); r[6]=(short)f2bf(hi.z); r[7]=(short)f2bf(hi.w);
  return r;
}

// ---------------- preA: WVO | G0/Q2S | qkmat | WVW — all independent ----------------
// grid = 256 + 168 + 256 + 256 = 936
__global__ __launch_bounds__(256) void preA(const float* __restrict__ latents,
    const float* __restrict__ wlq, const float* __restrict__ wck,
    const float* __restrict__ wcv, const float* __restrict__ wlo,
    const float* __restrict__ wlv, const float* __restrict__ wso,
    const float* __restrict__ gw1, const float* __restrict__ gb1,
    const float* __restrict__ qpos, const float* __restrict__ lemb,
    const float* __restrict__ wsq, float* __restrict__ ws)
{
  int bid = blockIdx.x, tid = threadIdx.x;
  if (bid < 256){                 // W_vo row d = bid
    const float* a = wcv + bid*ND;
    float acc = 0.f;
    #pragma unroll 8
    for (int k=0;k<ND;k++) acc += a[k]*wlo[k*ND+tid];
    ws[OFF_WVO + bid*ND + tid] = acc;
  } else if (bid < 256+NP){       // G0 / q2s row p
    int p = bid-256;
    float ag = gb1[tid], aq = 0.f;
    #pragma unroll 4
    for (int j=0;j<ND;j++){
      float sb = qpos[p*ND+j] + lemb[NP*ND+j];
      ag += sb*gw1[j*ND+tid];
      aq += sb*wsq[j*ND+tid];
    }
    ws[OFF_G0  + p*ND + tid] = ag;
    ws[OFF_Q2S + p*ND + tid] = aq*SCL;
  } else if (bid < 256+NP+256){   // qkmat column d (self-contained)
    int d = bid-(256+NP);
    __shared__ float ck[ND];
    __shared__ float red[4][NL];
    ck[tid] = wck[d*ND + tid];
    __syncthreads();
    const float* wrow = wlq + tid*ND;
    float macc = 0.f;
    #pragma unroll 8
    for (int k4=0;k4<64;k4++){
      float4 w4 = *(const float4*)(wrow + k4*4);
      float4 c4 = *(const float4*)(ck + k4*4);
      macc += w4.x*c4.x + w4.y*c4.y + w4.z*c4.z + w4.w*c4.w;
    }
    float part[NL];
    #pragma unroll
    for (int l=0;l<NL;l++) part[l] = latents[l*ND + tid]*macc;
    #pragma unroll
    for (int m=1;m<64;m<<=1){
      #pragma unroll
      for (int l=0;l<NL;l++) part[l] += __shfl_xor(part[l], m);
    }
    if ((tid&63)==0){
      #pragma unroll
      for (int l=0;l<NL;l++) red[tid>>6][l] = part[l];
    }
    __syncthreads();
    if (tid < NL){
      float s = red[0][tid]+red[1][tid]+red[2][tid]+red[3][tid];
      ws[OFF_QK + tid*ND + d] = s*SCL;
    }
  } else {                        // WVW row dd = wlv-row @ wso @ gw1b, on the fly
    int dd = bid-(256+NP+256);
    __shared__ float tmp[ND];
    const float* a = wlv + dd*ND;
    float t = 0.f;
    #pragma unroll 8
    for (int k=0;k<ND;k++) t += a[k]*wso[k*ND+tid];
    tmp[tid] = t;
    __syncthreads();
    const float* gw1b = gw1 + (size_t)ND*ND;
    float acc = 0.f;
    #pragma unroll 8
    for (int m=0;m<ND;m++) acc += tmp[m]*gw1b[m*ND+tid];
    ws[OFF_WVW + dd*ND + tid] = acc;
  }
}

// ---------------- kernel A v3: zero-barrier continuous async pipeline ----------------
// grid = 256 ; block 256 ; 1 block/CU. Block owns ctx rows [bid*1024, bid*1024+1024):
// 16 subs of 64 rows, double-buffered global->LDS DMA, waves fully independent
// (own 16 rows per buffer, own efull rows, per-wave AV/den partials to global).
__global__ __launch_bounds__(256,1) void kA(const float* __restrict__ ctx, float* __restrict__ ws)
{
  __shared__ float buf[2][64*256];  // 128KB
  __shared__ float efull[256*8];    // 8KB: e[sub*64 + row][l]

  int bid = blockIdx.x;
  int tid = threadIdx.x;
  int wv = tid >> 6, lane = tid & 63;
  int c = lane & 15, g = lane >> 4;
  int dq = lane;
  int rr = wv*16 + c, r7 = rr & 7;

  short8b afrag[8];
  if (c < NL){
    const float* qk = ws + OFF_QK + c*ND + g*8;
    #pragma unroll
    for (int kk=0;kk<8;kk++){
      float4 lo = *(const float4*)(qk + kk*32);
      float4 hi = *(const float4*)(qk + kk*32 + 4);
      afrag[kk] = pack8(lo, hi);
    }
  } else {
    short8b z;
    #pragma unroll
    for (int j=0;j<8;j++) z[j] = 0;
    #pragma unroll
    for (int kk=0;kk<8;kk++) afrag[kk] = z;
  }

  float av[8][4];
  float den8[8];
  #pragma unroll
  for (int l=0;l<8;l++){
    den8[l] = 0.f;
    #pragma unroll
    for (int j=0;j<4;j++) av[l][j] = 0.f;
  }

  int lofs[8];
  #pragma unroll
  for (int j=0;j<8;j++) lofs[j] = (lane ^ j) << 2;

  // wave's rows for sub 0
  const float* gw = ctx + ((size_t)bid*1024 + wv*16)*ND;

#define STAGE(PBUF, GPTR) do{                                                     \
    _Pragma("unroll")                                                             \
    for (int i_=0;i_<16;i_++){                                                    \
      __builtin_amdgcn_global_load_lds(                                           \
          (const __attribute__((address_space(1))) void*)((GPTR) + i_*ND + lofs[i_&7]), \
          (__attribute__((address_space(3))) void*)((PBUF) + (wv*16+i_)*256), 16, 0, 0); \
    }                                                                             \
  }while(0)

  STAGE(&buf[0][0], gw);

  #pragma unroll 1
  for (int s=0; s<16; ++s){
    float* pc = &buf[s&1][0];
    float* pn = &buf[(s&1)^1][0];
    int sub = s & 3;
    // my ds_reads on pn's rows (prev sub) must be retired before its new data lands
    asm volatile("s_waitcnt lgkmcnt(0)" ::: "memory");
    __builtin_amdgcn_sched_barrier(0);
    if (s < 15){
      STAGE(pn, gw + (size_t)(s+1)*64*ND);
      asm volatile("s_waitcnt vmcnt(16)" ::: "memory");   // current sub landed
    } else {
      asm volatile("s_waitcnt vmcnt(0)" ::: "memory");
    }
    __builtin_amdgcn_sched_barrier(0);

    // ---- phase 1: own rows -> MFMA -> e (own efull rows)
    f32x4 acc = {0.f,0.f,0.f,0.f};
    #pragma unroll
    for (int kk=0;kk<8;kk++){
      int sA = 2*g + 8*kk;
      float4 lo = *(const float4*)(pc + rr*256 + (((sA  ) ^ r7)<<2));
      float4 hi = *(const float4*)(pc + rr*256 + (((sA+1) ^ r7)<<2));
      acc = __builtin_amdgcn_mfma_f32_16x16x32_bf16(afrag[kk], pack8(lo,hi), acc, 0, 0, 0);
    }
    if (g < 2){
      float4 ev = make_float4(__expf(acc[0]),__expf(acc[1]),__expf(acc[2]),__expf(acc[3]));
      *(float4*)&efull[(sub*64 + rr)*8 + g*4] = ev;
    }
    asm volatile("s_waitcnt lgkmcnt(0)" ::: "memory");    // e visible to own wave
    __builtin_amdgcn_sched_barrier(0);

    // ---- phase 2: own 16 rows
    #pragma unroll
    for (int i=0;i<16;i++){
      int tl = wv*16 + i;
      float4 c4 = *(const float4*)(pc + tl*256 + ((dq ^ (tl&7))<<2));
      const float* ep = efull + (sub*64 + tl)*8;
      float4 e0 = *(const float4*)ep;
      float4 e1 = *(const float4*)(ep+4);
      float e8[8];
      e8[0]=e0.x; e8[1]=e0.y; e8[2]=e0.z; e8[3]=e0.w;
      e8[4]=e1.x; e8[5]=e1.y; e8[6]=e1.z; e8[7]=e1.w;
      #pragma unroll
      for (int l=0;l<8;l++){
        av[l][0] += e8[l]*c4.x;
        av[l][1] += e8[l]*c4.y;
        av[l][2] += e8[l]*c4.z;
        av[l][3] += e8[l]*c4.w;
        den8[l]  += e8[l];
      }
    }

    // ---- chunk epilogue: per-wave partials straight to global, no sync
    if (sub == 3){
      int cid = bid*4 + (s>>2);
      int pi  = cid*4 + wv;
      #pragma unroll
      for (int l=0;l<8;l++){
        *(float4*)&ws[OFF_AV + ((size_t)pi*8 + l)*ND + dq*4] =
            make_float4(av[l][0],av[l][1],av[l][2],av[l][3]);
        av[l][0]=0.f; av[l][1]=0.f; av[l][2]=0.f; av[l][3]=0.f;
      }
      if (lane == 0){
        *(float4*)&ws[OFF_DEN + pi*8    ] = make_float4(den8[0],den8[1],den8[2],den8[3]);
        *(float4*)&ws[OFF_DEN + pi*8 + 4] = make_float4(den8[4],den8[5],den8[6],den8[7]);
      }
      #pragma unroll
      for (int l=0;l<8;l++) den8[l] = 0.f;
    }
  }
#undef STAGE
}

// ---------------- kernel B1: 32-partial combine + lat_ctx + K2 + VW ----------------
// grid = 128 (per b)
__global__ __launch_bounds__(256) void kB1(const float* __restrict__ wlk,
                                           float* __restrict__ ws)
{
  int b = blockIdx.x;
  int d = threadIdx.x;
  __shared__ float avnT[256][8];
  __shared__ float latT[256][8];

  float dent[8];
  #pragma unroll
  for (int l=0;l<8;l++) dent[l] = 0.f;
  #pragma unroll 4
  for (int j=0;j<32;j++){
    const float* dp = ws + OFF_DEN + (size_t)(b*32+j)*8;
    float4 d0 = *(const float4*)dp;
    float4 d1 = *(const float4*)(dp+4);
    dent[0]+=d0.x; dent[1]+=d0.y; dent[2]+=d0.z; dent[3]+=d0.w;
    dent[4]+=d1.x; dent[5]+=d1.y; dent[6]+=d1.z; dent[7]+=d1.w;
  }
  float av8[8];
  #pragma unroll
  for (int l=0;l<8;l++) av8[l] = 0.f;
  #pragma unroll 2
  for (int j=0;j<32;j++){
    size_t base = OFF_AV + ((size_t)(b*32+j))*8*ND + d;
    #pragma unroll
    for (int l=0;l<8;l++) av8[l] += ws[base + (size_t)l*ND];
  }
  #pragma unroll
  for (int l=0;l<8;l++) av8[l] /= dent[l];
  *(float4*)&avnT[d][0] = make_float4(av8[0],av8[1],av8[2],av8[3]);
  *(float4*)&avnT[d][4] = make_float4(av8[4],av8[5],av8[6],av8[7]);
  __syncthreads();

  float lc[8];
  #pragma unroll
  for (int l=0;l<8;l++) lc[l] = 0.f;
  #pragma unroll 8
  for (int dd=0;dd<ND;dd++){
    float w = ws[OFF_WVO + dd*ND + d];
    float4 a0 = *(const float4*)&avnT[dd][0];
    float4 a1 = *(const float4*)&avnT[dd][4];
    lc[0]+=a0.x*w; lc[1]+=a0.y*w; lc[2]+=a0.z*w; lc[3]+=a0.w*w;
    lc[4]+=a1.x*w; lc[5]+=a1.y*w; lc[6]+=a1.z*w; lc[7]+=a1.w*w;
  }
  *(float4*)&latT[d][0] = make_float4(lc[0],lc[1],lc[2],lc[3]);
  *(float4*)&latT[d][4] = make_float4(lc[4],lc[5],lc[6],lc[7]);
  __syncthreads();

  float k2a[8], vwa[8];
  #pragma unroll
  for (int l=0;l<8;l++){ k2a[l]=0.f; vwa[l]=0.f; }
  #pragma unroll 8
  for (int dd=0;dd<ND;dd++){
    float wk = wlk[dd*ND + d];
    float wvv = ws[OFF_WVW + dd*ND + d];
    float4 a0 = *(const float4*)&latT[dd][0];
    float4 a1 = *(const float4*)&latT[dd][4];
    k2a[0]+=a0.x*wk; k2a[1]+=a0.y*wk; k2a[2]+=a0.z*wk; k2a[3]+=a0.w*wk;
    k2a[4]+=a1.x*wk; k2a[5]+=a1.y*wk; k2a[6]+=a1.z*wk; k2a[7]+=a1.w*wk;
    vwa[0]+=a0.x*wvv; vwa[1]+=a0.y*wvv; vwa[2]+=a0.z*wvv; vwa[3]+=a0.w*wvv;
    vwa[4]+=a1.x*wvv; vwa[5]+=a1.y*wvv; vwa[6]+=a1.z*wvv; vwa[7]+=a1.w*wvv;
  }
  #pragma unroll
  for (int l=0;l<8;l++){
    ws[OFF_K2 + (size_t)b*8*ND + l*ND + d] = k2a[l];
    ws[OFF_VW + (size_t)b*8*ND + l*ND + d] = vwa[l];
  }
}

// ---------------- kernel B2: attn2 weights + gate + top2 + output ----------------
__global__ __launch_bounds__(256) void kB2(const float* __restrict__ ws,
    const float* __restrict__ gw2, const float* __restrict__ gb2,
    const float* __restrict__ qe, float* __restrict__ out)
{
  int bid = blockIdx.x;
  int b = bid / 6, p0 = (bid % 6)*28;
  int tid = threadIdx.x;

  __shared__ float q2h[28][260];
  __shared__ float k2s[8][260];
  __shared__ float vws[8][260];
  __shared__ float wexp[28][8];
  __shared__ float lg[28][33];
  __shared__ float4 sel[28];

  #pragma unroll
  for (int i=0;i<7;i++){
    int idx = tid + i*256;
    int r = idx >> 6, c4 = idx & 63;
    *(float4*)&q2h[r][c4*4] = *(const float4*)&ws[OFF_Q2S + (p0+r)*ND + c4*4];
  }
  #pragma unroll
  for (int i=0;i<2;i++){
    int idx = tid + i*256;
    int l = idx >> 6, c4 = idx & 63;
    *(float4*)&k2s[l][c4*4] = *(const float4*)&ws[OFF_K2 + (size_t)(b*8+l)*ND + c4*4];
    *(float4*)&vws[l][c4*4] = *(const float4*)&ws[OFF_VW + (size_t)(b*8+l)*ND + c4*4];
  }
  __syncthreads();

  {
    int pp = tid >> 3, l1 = tid & 7;
    if (pp < 28){
      float s2 = 0.f;
      #pragma unroll 8
      for (int i=0;i<64;i++){
        float4 qa = *(const float4*)&q2h[pp][4*i];
        float4 kb = *(const float4*)&k2s[l1][4*i];
        s2 += qa.x*kb.x + qa.y*kb.y + qa.z*kb.z + qa.w*kb.w;
      }
      float e2 = __expf(s2);
      float den = e2;
      den += __shfl_xor(den,1); den += __shfl_xor(den,2); den += __shfl_xor(den,4);
      wexp[pp][l1] = e2/den;
    }
  }
  __syncthreads();

  {
    float vcol[8];
    #pragma unroll
    for (int l=0;l<8;l++) vcol[l] = vws[l][tid];
    #pragma unroll 4
    for (int p=0;p<28;p++){
      float4 w0 = *(const float4*)&wexp[p][0];
      float4 w1v = *(const float4*)&wexp[p][4];
      float x = ws[OFF_G0 + (p0+p)*ND + tid]
              + w0.x*vcol[0]+w0.y*vcol[1]+w0.z*vcol[2]+w0.w*vcol[3]
              + w1v.x*vcol[4]+w1v.y*vcol[5]+w1v.z*vcol[6]+w1v.w*vcol[7];
      q2h[p][tid] = 0.5f*x*(1.f+erff(x*0.70710678118654752f));
    }
  }
  __syncthreads();

  {
    int e = tid & 31, pq = tid >> 5;
    if (pq < 7){
      float b2v = gb2[e];
      float a0=b2v, a1=b2v, a2=b2v, a3=b2v;
      for (int cc=0;cc<ND;cc+=4){
        float w20 = gw2[(cc+0)*NE + e];
        float w21 = gw2[(cc+1)*NE + e];
        float w22 = gw2[(cc+2)*NE + e];
        float w23 = gw2[(cc+3)*NE + e];
        float4 h0 = *(const float4*)&q2h[pq*4+0][cc];
        float4 h1 = *(const float4*)&q2h[pq*4+1][cc];
        float4 h2 = *(const float4*)&q2h[pq*4+2][cc];
        float4 h3 = *(const float4*)&q2h[pq*4+3][cc];
        a0 += h0.x*w20 + h0.y*w21 + h0.z*w22 + h0.w*w23;
        a1 += h1.x*w20 + h1.y*w21 + h1.z*w22 + h1.w*w23;
        a2 += h2.x*w20 + h2.y*w21 + h2.z*w22 + h2.w*w23;
        a3 += h3.x*w20 + h3.y*w21 + h3.z*w22 + h3.w*w23;
      }
      lg[pq*4+0][e] = a0;
      lg[pq*4+1][e] = a1;
      lg[pq*4+2][e] = a2;
      lg[pq*4+3][e] = a3;
    }
  }
  __syncthreads();

  if (tid < 28){
    float m1 = -1e30f, m2 = -1e30f;
    int e1 = 0, ee2 = 0;
    for (int e3=0;e3<NE;e3++){
      float v = lg[tid][e3];
      if (v > m1){ m2 = m1; ee2 = e1; m1 = v; e1 = e3; }
      else if (v > m2){ m2 = v; ee2 = e3; }
    }
    float z = __expf(m2 - m1);
    float inv = 1.f/(1.f+z);
    sel[tid] = make_float4(__int_as_float(e1), __int_as_float(ee2), inv, z*inv);
  }
  __syncthreads();

  for (int p=0;p<28;p++){
    float4 s = sel[p];
    int e1 = __float_as_int(s.x), ee2 = __float_as_int(s.y);
    float q1v = qe[((size_t)e1*NP + (p0+p))*ND + tid];
    float q2v = qe[((size_t)ee2*NP + (p0+p))*ND + tid];
    out[((size_t)b*NP + (p0+p))*ND + tid] = s.z*q1v + s.w*q2v;
  }
}

extern "C" void kernel_launch(void* const* d_in, const int* in_sizes, int n_in,
                              void* d_out, int out_size, void* d_ws, size_t ws_size,
                              hipStream_t stream)
{
  const float* ctx  = (const float*)d_in[0];
  const float* qe   = (const float*)d_in[1];
  const float* qpos = (const float*)d_in[2];
  const float* lemb = (const float*)d_in[3];
  const float* lat  = (const float*)d_in[4];
  const float* wlq  = (const float*)d_in[5];
  const float* wck  = (const float*)d_in[6];
  const float* wcv  = (const float*)d_in[7];
  const float* wlo  = (const float*)d_in[8];
  const float* wsq  = (const float*)d_in[9];
  const float* wlk  = (const float*)d_in[10];
  const float* wlv  = (const float*)d_in[11];
  const float* wso  = (const float*)d_in[12];
  const float* gw1  = (const float*)d_in[13];
  const float* gb1  = (const float*)d_in[14];
  const float* gw2  = (const float*)d_in[15];
  const float* gb2  = (const float*)d_in[16];
  float* out = (float*)d_out;
  float* ws  = (float*)d_ws;

  preA<<<256+NP+256+256, 256, 0, stream>>>(lat, wlq, wck, wcv, wlo, wlv, wso,
                                           gw1, gb1, qpos, lemb, wsq, ws);
  kA  <<<256, 256, 0, stream>>>(ctx, ws);
  kB1 <<<NB, 256, 0, stream>>>(wlk, ws);
  kB2 <<<NB*6, 256, 0, stream>>>(ws, gw2, gb2, qe, out);
}